// Round 6
// baseline (220.005 us; speedup 1.0000x reference)
//
#include <hip/hip_runtime.h>
#include <math.h>

#define BB 32
#define HH 256
#define WW 256
#define HW (HH*WW)
#define K_BG 0.1f
#define RELAX 5.0f
#define EPS_D 1e-7
#define RPB 8                          // rows per block (R0/R5-proven geometry)
#define NBLK (BB * (HH / RPB))         // 1024 = exactly 4 blocks/CU x 256 CUs

typedef unsigned long long u64;

__device__ __forceinline__ float sigf(float x) { return 1.0f / (1.0f + expf(-x)); }

__device__ __forceinline__ u64 shflx64(u64 x, int s) {
    return (u64)__shfl_xor((unsigned long long)x, s, 64);
}

// ONE regular-launch kernel (cooperative launch failed under graph capture in
// R4). Software grid barrier: grid == exact resident capacity (1024 blocks at
// __launch_bounds__(256,4), 17.7KB LDS), ticket + threadfence pattern proven
// by R5's fused tail. Bounded spin converts hypothetical deadlock into a
// wrong-answer failure rather than a hang. cnt[0]=barrier, cnt[1]=fold ticket;
// both pre-zeroed by hipMemsetAsync in kernel_launch (capture-legal).
// Phase A: each block bit-dilates its own 8-row band (12-row halo) -- proven
//          maskdil math re-banded; raw nz bits stay in LDS; preds loads
//          issued first and consumed in phase C (HBM latency hidden).
// Barrier (the per-image all-to-all dependency of the vertical EDT).
// Phase B/C/D: R5's proven transpose + walk + partials + fused fold, verbatim.
__global__ __launch_bounds__(256, 4) void k_fused(const float* __restrict__ preds,
                                                  const float* __restrict__ tg,
                                                  u64* __restrict__ dmaskT,
                                                  float4* __restrict__ part1,
                                                  float4* __restrict__ part2,
                                                  unsigned* __restrict__ cnt,
                                                  float* __restrict__ out) {
    __shared__ u64 nz[12][4];          // raw ballots, rows i0-2 .. i0+9
    __shared__ u64 hd[12][4];          // horizontally dilated
    __shared__ u64 colT[4 * 256];      // [rowgroup g][col]: bits = rows 64g..64g+63
    __shared__ float gS[RPB][WW];
    __shared__ float red[8][4];
    __shared__ unsigned stick;
    __shared__ float sI[BB], sC[BB], sA[BB];

    int blk = blockIdx.x;              // b*32 + q ; rows 8q..8q+7
    int b = blk >> 5, q = blk & 31;
    int i0 = q * RPB;
    int tid = threadIdx.x;
    int lane = tid & 63, wv = tid >> 6;
    int j = tid;                       // this thread's column

    // ---- preds preload: in flight through phase A + barrier ----
    float p[RPB];
    #pragma unroll
    for (int rr = 0; rr < RPB; ++rr)
        p[rr] = preds[(b * HH + i0 + rr) * WW + j];

    // ---- phase A: band dilation (proven maskdil math, 8-row band) ----
    const float* img = tg + b * HW;
    float v[12];
    #pragma unroll
    for (int rr = 0; rr < 12; ++rr) {  // halo rows i0-2 .. i0+9
        int rg = i0 + rr - 2;
        v[rr] = (rg >= 0 && rg < HH) ? img[rg * WW + j] : 0.0f;
    }
    #pragma unroll
    for (int rr = 0; rr < 12; ++rr) {
        u64 bal = __ballot(v[rr] != 0.0f);
        if (lane == 0) nz[rr][wv] = bal;
    }
    __syncthreads();
    if (tid < 48) {                    // 12 rows x 4 words: horizontal +-2 dilate
        int lr = tid >> 2, k = tid & 3;
        u64 m = nz[lr][k];
        u64 ml = (k > 0) ? nz[lr][k - 1] : 0ULL;
        u64 mr = (k < 3) ? nz[lr][k + 1] : 0ULL;
        hd[lr][k] = m | (m << 1) | (m << 2) | (m >> 1) | (m >> 2)
                  | (ml >> 62) | (ml >> 63) | (mr << 62) | (mr << 63);
    }
    __syncthreads();
    if (tid < 32) {                    // 8 owned rows x 4 words: vertical +-2 dilate
        int rr = tid >> 2, k = tid & 3;
        u64 o = hd[rr][k] | hd[rr + 1][k] | hd[rr + 2][k] | hd[rr + 3][k] | hd[rr + 4][k];
        dmaskT[b * 1024 + k * 256 + (i0 + rr)] = o;   // word-major
    }
    u64 nzw[RPB];                      // raw target word (row i0+rr, word wv)
    #pragma unroll
    for (int rr = 0; rr < RPB; ++rr) nzw[rr] = nz[rr + 2][wv];
    __syncthreads();                   // drain dmaskT stores (barrier waits vmcnt)

    // ---- software grid barrier (ticket pattern proven in R5 tail) ----
    if (tid == 0) {
        __threadfence();               // release this block's dmaskT writes
        atomicAdd(&cnt[0], 1u);
        int spins = 0;
        while (atomicAdd(&cnt[0], 0u) < NBLK) {
            __builtin_amdgcn_s_sleep(8);
            if (++spins > 200000) break;   // ~40ms: deadlock -> wrong answer, not hang
        }
    }
    __syncthreads();
    __threadfence();                   // acquire all blocks' dmaskT writes

    // ---- phase B: register bit-transpose: wave wv owns rowgroup wv ----
    const u64* base = dmaskT + b * 1024;
    const u64 L32 = 0x00000000FFFFFFFFULL, L16 = 0x0000FFFF0000FFFFULL,
              L8  = 0x00FF00FF00FF00FFULL, L4  = 0x0F0F0F0F0F0F0F0FULL,
              L2  = 0x3333333333333333ULL, L1  = 0x5555555555555555ULL;
    #pragma unroll
    for (int w = 0; w < 4; ++w) {
        u64 x = base[w * 256 + wv * 64 + lane];   // row (64wv+lane), word w
        u64 pp;
        pp = shflx64(x, 32); x = (lane & 32) ? ((x & ~L32) | ((pp & ~L32) >> 32)) : ((x & L32) | ((pp & L32) << 32));
        pp = shflx64(x, 16); x = (lane & 16) ? ((x & ~L16) | ((pp & ~L16) >> 16)) : ((x & L16) | ((pp & L16) << 16));
        pp = shflx64(x,  8); x = (lane &  8) ? ((x & ~L8 ) | ((pp & ~L8 ) >>  8)) : ((x & L8 ) | ((pp & L8 ) <<  8));
        pp = shflx64(x,  4); x = (lane &  4) ? ((x & ~L4 ) | ((pp & ~L4 ) >>  4)) : ((x & L4 ) | ((pp & L4 ) <<  4));
        pp = shflx64(x,  2); x = (lane &  2) ? ((x & ~L2 ) | ((pp & ~L2 ) >>  2)) : ((x & L2 ) | ((pp & L2 ) <<  2));
        pp = shflx64(x,  1); x = (lane &  1) ? ((x & ~L1 ) | ((pp & ~L1 ) >>  1)) : ((x & L1 ) | ((pp & L1 ) <<  1));
        colT[wv * 256 + w * 64 + lane] = x;       // column (64w+lane), rowgroup wv
    }
    __syncthreads();

    u64 yw[4];                         // set bit = zero pixel, column j
    #pragma unroll
    for (int g = 0; g < 4; ++g) yw[g] = ~colT[g * 256 + j];

    // ---- branchless vertical distance for RPB pixels (same column) ----
    int g0v[RPB], fgv[RPB];
    #pragma unroll
    for (int rr = 0; rr < RPB; ++rr) {
        int i = i0 + rr;
        int iw = i >> 6, ib = i & 63;
        u64 lowm  = (2ULL << ib) - 1ULL;          // bits 0..ib (ib=63 -> ~0)
        u64 highm = ~((1ULL << ib) - 1ULL);       // bits ib..63
        int pu = -1, pd = -1;
        #pragma unroll
        for (int w = 0; w < 4; ++w) {             // ascending: highest nonzero word wins
            u64 m = (w < iw) ? ~0ULL : ((w == iw) ? lowm : 0ULL);
            u64 z = yw[w] & m;
            int cand = (w << 6) + 63 - __clzll(z);
            pu = z ? cand : pu;
        }
        #pragma unroll
        for (int w = 3; w >= 0; --w) {            // descending: lowest nonzero word wins
            u64 m = (w > iw) ? ~0ULL : ((w == iw) ? highm : 0ULL);
            u64 z = yw[w] & m;
            int cand = (w << 6) + (__ffsll((unsigned long long)z) - 1);
            pd = z ? cand : pd;
        }
        int up = (pu >= 0) ? (i - pu) : 10000;
        int dn = (pd >= 0) ? (pd - i) : 10000;
        int g0 = min(min(up, dn), 10000);
        g0v[rr] = g0;
        fgv[rr] = (int)((~yw[iw] >> ib) & 1ULL);
        gS[rr][j] = (float)g0;
    }
    __syncthreads();

    // ---- phase C: row-at-a-time min-plus walk + dice partials (R5 verbatim) ----
    float vals[8];
    #pragma unroll
    for (int qq = 0; qq < 6; ++qq) vals[qq] = 0.0f;
    vals[6] = 1e30f; vals[7] = 0.0f;
    #pragma unroll
    for (int rr = 0; rr < RPB; ++rr) {
        float gv = (float)g0v[rr];
        float best = gv * gv;
        #pragma unroll
        for (int r = 1; r <= 8; ++r) {            // branchless prefix
            float rf = (float)(r * r);
            int jl = j - r, jr = j + r;
            float vl = (jl >= 0) ? gS[rr][jl] : 1e4f;
            float vr = (jr < WW) ? gS[rr][jr] : 1e4f;
            best = fminf(best, fminf(fmaf(vl, vl, rf), fmaf(vr, vr, rf)));
        }
        for (int rc = 9; rc < WW + 8; rc += 8) {  // branchless 8-chunks, 1 test/chunk
            if ((float)(rc * rc) >= best) break;
            #pragma unroll
            for (int dr = 0; dr < 8; ++dr) {
                int r = rc + dr;
                float rf = (float)(r * r);
                int jl = j - r, jr = j + r;
                float vl = (jl >= 0) ? gS[rr][jl] : 1e4f;
                float vr = (jr < WW) ? gS[rr][jr] : 1e4f;
                best = fminf(best, fminf(fmaf(vl, vl, rf), fmaf(vr, vr, rf)));
            }
        }
        float dv = sqrtf(best);
        float sp = sigf(p[rr]);
        float sd = sigf(dv / RELAX);
        float tv = (float)((nzw[rr] >> (j & 63)) & 1ULL);
        vals[0] += sp * sd * tv;                  // A
        vals[1] += sp * tv;                       // B
        vals[2] += sp * sd;                       // A'
        vals[3] += sp;                            // B'
        vals[4] += fgv[rr] ? 0.0f : sp;           // C' = sp*(1-fat)
        vals[5] += tv;                            // T
        vals[6] = fminf(vals[6], dv);
        vals[7] = fmaxf(vals[7], dv);
    }
    for (int off = 32; off > 0; off >>= 1) {
        #pragma unroll
        for (int qq = 0; qq < 6; ++qq) vals[qq] += __shfl_down(vals[qq], off, 64);
        vals[6] = fminf(vals[6], __shfl_down(vals[6], off, 64));
        vals[7] = fmaxf(vals[7], __shfl_down(vals[7], off, 64));
    }
    if (lane == 0) {
        #pragma unroll
        for (int qq = 0; qq < 8; ++qq) red[qq][wv] = vals[qq];
    }
    __syncthreads();
    if (tid == 0) {
        float s[8];
        #pragma unroll
        for (int qq = 0; qq < 6; ++qq) s[qq] = red[qq][0] + red[qq][1] + red[qq][2] + red[qq][3];
        s[6] = fminf(fminf(red[6][0], red[6][1]), fminf(red[6][2], red[6][3]));
        s[7] = fmaxf(fmaxf(red[7][0], red[7][1]), fmaxf(red[7][2], red[7][3]));
        part1[blk] = make_float4(s[0], s[1], s[2], s[3]);
        part2[blk] = make_float4(s[4], s[5], s[6], s[7]);
        __threadfence();                          // release partials
        stick = atomicAdd(&cnt[1], 1u);
    }
    __syncthreads();
    if (stick != NBLK - 1) return;

    // ---- phase D: last block folds 32 partials/image (R5-proven) ----
    __threadfence();                              // acquire partials
    #pragma unroll
    for (int pass = 0; pass < 4; ++pass) {
        int img2 = pass * 8 + (tid >> 5);         // 8 images per pass, 32 lanes each
        int k = tid & 31;
        float4 p1 = part1[img2 * 32 + k];
        float4 p2 = part2[img2 * 32 + k];
        float v2[8] = {p1.x, p1.y, p1.z, p1.w, p2.x, p2.y, p2.z, p2.w};
        for (int off = 16; off > 0; off >>= 1) {
            #pragma unroll
            for (int qq = 0; qq < 6; ++qq) v2[qq] += __shfl_down(v2[qq], off, 32);
            v2[6] = fminf(v2[6], __shfl_down(v2[6], off, 32));
            v2[7] = fmaxf(v2[7], __shfl_down(v2[7], off, 32));
        }
        if (k == 0) {
            float A = v2[0], Bs = v2[1], Ap = v2[2], Bp = v2[3];
            float Cp = v2[4], T = v2[5], dmn = v2[6], dmx = v2[7];
            float inter, card, any;
            if (dmx > 0.0f) {          // image has foreground
                float smin = sigf(dmn / RELAX);
                float smax = sigf(dmx / RELAX);
                float m = smax - smin;
                float denom = (m > 0.0f) ? m : 1.0f;
                inter = (A - smin * Bs) / denom;   // Σ sp·t·(1-fat) == 0 exactly
                card  = (Ap - smin * Bp) / denom + K_BG * Cp + T;
                any = 1.0f;
            } else {                   // dm = 1 - t ; t == 0 everywhere
                inter = 0.0f;
                card = Bp - Bs + T;
                any = 0.0f;
            }
            sI[img2] = inter; sC[img2] = card; sA[img2] = any;
        }
    }
    __syncthreads();
    if (tid == 0) {
        double I = 0.0, C = 0.0;
        int any = 0;
        for (int bb = 0; bb < BB; ++bb) {
            I += (double)sI[bb]; C += (double)sC[bb];
            any |= (sA[bb] > 0.0f);
        }
        double dice = 2.0 * I / fmax(C, (double)EPS_D);
        out[0] = any ? (float)(1.0 - dice) : 0.0f;
    }
}

extern "C" void kernel_launch(void* const* d_in, const int* in_sizes, int n_in,
                              void* d_out, int out_size, void* d_ws, size_t ws_size,
                              hipStream_t stream) {
    const float* preds = (const float*)d_in[0];
    const float* tg    = (const float*)d_in[1];
    float* out = (float*)d_out;

    u64* dmaskT   = (u64*)d_ws;                      // 256 KB
    float4* part1 = (float4*)(dmaskT + BB * 1024);   // 16 KB, 16B-aligned
    float4* part2 = part1 + NBLK;                    // 16 KB
    unsigned* cnt = (unsigned*)(part2 + NBLK);       // cnt[0]=barrier, cnt[1]=fold

    hipMemsetAsync(cnt, 0, 2 * sizeof(unsigned), stream);   // capture-legal
    hipLaunchKernelGGL(k_fused, dim3(NBLK), dim3(256), 0, stream,
                       preds, tg, dmaskT, part1, part2, cnt, out);
}

// Round 7
// 98.176 us; speedup vs baseline: 2.2409x; 2.2409x over previous
//
#include <hip/hip_runtime.h>
#include <math.h>

#define BB 32
#define HH 256
#define WW 256
#define HW (HH*WW)
#define K_BG 0.1f
#define RELAX 5.0f
#define EPS_D 1e-7
#define RPB 8                          // rows per k_mega BLOCK (amortization unit)
#define RPT 4                          // rows per THREAD (512-thread blocks)
#define MEGA_BLOCKS (BB * (HH / RPB))  // 1024 blocks x 512 thr = 2048 thr/CU (full)

typedef unsigned long long u64;

__device__ __forceinline__ float sigf(float x) { return 1.0f / (1.0f + expf(-x)); }

__device__ __forceinline__ u64 shflx64(u64 x, int s) {
    return (u64)__shfl_xor((unsigned long long)x, s, 64);
}

// ---------------- binary 5x5 dilation as bit-ops -> row masks ----------------
// R0/R5-proven structure: 512 blocks x 256 threads (16-row bands).
__global__ void k_maskdil(const float* __restrict__ tg, u64* __restrict__ dmaskT,
                          u64* __restrict__ nzmask, unsigned* __restrict__ cnt) {
    __shared__ u64 nz[20][4];
    __shared__ u64 hd[20][4];
    int blk = blockIdx.x;              // 32 images x 16 bands of 16 rows
    int b = blk >> 4, band = blk & 15;
    int r0 = band * 16;
    int t = threadIdx.x, w = t >> 6;
    const float* img = tg + b * HW;
    if (blk == 0 && t == 0) cnt[0] = 0;      // ticket reset (R5-proven)
    float v[20];
    #pragma unroll
    for (int rr = 0; rr < 20; ++rr) {
        int rg = r0 + rr - 2;
        v[rr] = (rg >= 0 && rg < HH) ? img[rg * WW + t] : 0.0f;
    }
    #pragma unroll
    for (int rr = 0; rr < 20; ++rr) {
        u64 bal = __ballot(v[rr] != 0.0f);
        if ((t & 63) == 0) nz[rr][w] = bal;
    }
    __syncthreads();
    if (t < 80) {                      // 20 rows x 4 words: horizontal +-2 dilate
        int rr = t >> 2, k = t & 3;
        u64 m = nz[rr][k];
        u64 ml = (k > 0) ? nz[rr][k - 1] : 0ULL;
        u64 mr = (k < 3) ? nz[rr][k + 1] : 0ULL;
        hd[rr][k] = m | (m << 1) | (m << 2) | (m >> 1) | (m >> 2)
                  | (ml >> 62) | (ml >> 63) | (mr << 62) | (mr << 63);
    }
    if (t < 64) {                      // raw masks for the 16 owned rows
        int rr = t >> 2, k = t & 3;
        nzmask[b * 1024 + (r0 + rr) * 4 + k] = nz[rr + 2][k];
    }
    __syncthreads();
    if (t < 64) {                      // 16 rows x 4 words: vertical +-2 dilate
        int rr = t >> 2, k = t & 3;
        u64 o = hd[rr][k] | hd[rr + 1][k] | hd[rr + 2][k] | hd[rr + 3][k] | hd[rr + 4][k];
        dmaskT[b * 1024 + k * 256 + (r0 + rr)] = o;   // word-major
    }
}

// ---------------- mega: 512 threads -> full CU occupancy -----------------------
// R6 post-mortem: overhead is graph-fixed (~42us); only kernel time counts.
// mega was latency-bound at 16 waves/CU (VALUBusy 31%). Fix: 512-thread blocks,
// SAME 1024-block grid and RPB=8 -> 2048 thr/CU (32 waves, full), per-block
// work (transpose, reductions) NOT duplicated (R2's mistake). Each thread owns
// 4 rows; 8 waves split the 16 transpose (rowgroup,word) tasks 2-each.
// Sparsity skip: wave-rows with no fat pixel (ballot==0, ~24%) skip the clz
// machinery + entire walk -- exact (own-column candidate gives d=0).
__global__ __launch_bounds__(512, 8) void k_mega(const float* __restrict__ preds,
                                                 const u64* __restrict__ dmaskT,
                                                 const u64* __restrict__ nzmask,
                                                 float4* __restrict__ part1,
                                                 float4* __restrict__ part2,
                                                 unsigned* __restrict__ cnt,
                                                 float* __restrict__ out) {
    __shared__ u64 colT[4 * 256];      // [rowgroup g][col] : bits = rows 64g..64g+63
    __shared__ float gS[RPB][WW];
    __shared__ float red[8][8];
    __shared__ unsigned stick;
    __shared__ float sI[BB], sC[BB], sA[BB];
    int blk = blockIdx.x;              // b*32 + q ; rows 8q..8q+7
    int b = blk >> 5, q = blk & 31;
    int i0 = q * RPB;
    int tid = threadIdx.x;
    int lane = tid & 63, wv = tid >> 6;      // 8 waves
    int j = tid & 255;                 // this thread's column
    int r0t = (tid >> 8) * RPT;        // row-half: 0 or 4

    float p[RPT];                      // issue HBM loads first; consumed much later
    #pragma unroll
    for (int rr = 0; rr < RPT; ++rr)
        p[rr] = preds[(b * HH + i0 + r0t + rr) * WW + j];
    int wj = j >> 6;                   // word index of this column
    u64 nzw[RPT];
    #pragma unroll
    for (int rr = 0; rr < RPT; ++rr)
        nzw[rr] = nzmask[b * 1024 + (i0 + r0t + rr) * 4 + wj];

    // ---- register bit-transpose: 16 (g,w) tasks over 8 waves, 2 each ----
    const u64* base = dmaskT + b * 1024;
    const u64 L32 = 0x00000000FFFFFFFFULL, L16 = 0x0000FFFF0000FFFFULL,
              L8  = 0x00FF00FF00FF00FFULL, L4  = 0x0F0F0F0F0F0F0F0FULL,
              L2  = 0x3333333333333333ULL, L1  = 0x5555555555555555ULL;
    int tg_ = wv & 3, w0 = (wv >> 2) * 2;
    #pragma unroll
    for (int dw = 0; dw < 2; ++dw) {
        int w = w0 + dw;
        u64 x = base[w * 256 + tg_ * 64 + lane];  // row (64g+lane), word w
        u64 pp;
        pp = shflx64(x, 32); x = (lane & 32) ? ((x & ~L32) | ((pp & ~L32) >> 32)) : ((x & L32) | ((pp & L32) << 32));
        pp = shflx64(x, 16); x = (lane & 16) ? ((x & ~L16) | ((pp & ~L16) >> 16)) : ((x & L16) | ((pp & L16) << 16));
        pp = shflx64(x,  8); x = (lane &  8) ? ((x & ~L8 ) | ((pp & ~L8 ) >>  8)) : ((x & L8 ) | ((pp & L8 ) <<  8));
        pp = shflx64(x,  4); x = (lane &  4) ? ((x & ~L4 ) | ((pp & ~L4 ) >>  4)) : ((x & L4 ) | ((pp & L4 ) <<  4));
        pp = shflx64(x,  2); x = (lane &  2) ? ((x & ~L2 ) | ((pp & ~L2 ) >>  2)) : ((x & L2 ) | ((pp & L2 ) <<  2));
        pp = shflx64(x,  1); x = (lane &  1) ? ((x & ~L1 ) | ((pp & ~L1 ) >>  1)) : ((x & L1 ) | ((pp & L1 ) <<  1));
        colT[tg_ * 256 + w * 64 + lane] = x;      // column (64w+lane), rowgroup g
    }
    __syncthreads();

    u64 yw[4];                         // set bit = zero pixel, column j
    #pragma unroll
    for (int g = 0; g < 4; ++g) yw[g] = ~colT[g * 256 + j];

    // ---- vertical distance for this thread's 4 rows, with wave-skip ----
    int g0v[RPT], fgv[RPT], needw[RPT];
    #pragma unroll
    for (int rr = 0; rr < RPT; ++rr) {
        int i = i0 + r0t + rr;
        int iw = i >> 6, ib = i & 63;
        int fg = (int)((~yw[iw] >> ib) & 1ULL);   // 1 = fat pixel
        fgv[rr] = fg;
        u64 anyf = __ballot(fg != 0);             // wave-row fat occupancy
        needw[rr] = (anyf != 0ULL);
        int g0 = 0;
        if (anyf) {                               // ~76% of wave-rows
            u64 lowm  = (2ULL << ib) - 1ULL;      // bits 0..ib (ib=63 -> ~0)
            u64 highm = ~((1ULL << ib) - 1ULL);   // bits ib..63
            int pu = -1, pd = -1;
            #pragma unroll
            for (int w = 0; w < 4; ++w) {         // ascending: highest nonzero wins
                u64 m = (w < iw) ? ~0ULL : ((w == iw) ? lowm : 0ULL);
                u64 z = yw[w] & m;
                int cand = (w << 6) + 63 - __clzll(z);
                pu = z ? cand : pu;
            }
            #pragma unroll
            for (int w = 3; w >= 0; --w) {        // descending: lowest nonzero wins
                u64 m = (w > iw) ? ~0ULL : ((w == iw) ? highm : 0ULL);
                u64 z = yw[w] & m;
                int cand = (w << 6) + (__ffsll((unsigned long long)z) - 1);
                pd = z ? cand : pd;
            }
            int up = (pu >= 0) ? (i - pu) : 10000;
            int dn = (pd >= 0) ? (pd - i) : 10000;
            g0 = min(min(up, dn), 10000);
        }
        g0v[rr] = g0;
        gS[r0t + rr][j] = (float)g0;
    }
    __syncthreads();

    // ---- row-at-a-time min-plus walk + dice partials (walk skipped if no fat) ----
    float vals[8];
    #pragma unroll
    for (int qq = 0; qq < 6; ++qq) vals[qq] = 0.0f;
    vals[6] = 1e30f; vals[7] = 0.0f;
    #pragma unroll
    for (int rr = 0; rr < RPT; ++rr) {
        int rt = r0t + rr;
        float gv = (float)g0v[rr];
        float best = gv * gv;
        if (needw[rr]) {
            #pragma unroll
            for (int r = 1; r <= 8; ++r) {        // branchless prefix
                float rf = (float)(r * r);
                int jl = j - r, jr = j + r;
                float vl = (jl >= 0) ? gS[rt][jl] : 1e4f;
                float vr = (jr < WW) ? gS[rt][jr] : 1e4f;
                best = fminf(best, fminf(fmaf(vl, vl, rf), fmaf(vr, vr, rf)));
            }
            for (int rc = 9; rc < WW + 8; rc += 8) {  // rare exact tail
                if ((float)(rc * rc) >= best) break;
                #pragma unroll
                for (int dr = 0; dr < 8; ++dr) {
                    int r = rc + dr;
                    float rf = (float)(r * r);
                    int jl = j - r, jr = j + r;
                    float vl = (jl >= 0) ? gS[rt][jl] : 1e4f;
                    float vr = (jr < WW) ? gS[rt][jr] : 1e4f;
                    best = fminf(best, fminf(fmaf(vl, vl, rf), fmaf(vr, vr, rf)));
                }
            }
        }
        float dv = sqrtf(best);
        float sp = sigf(p[rr]);
        float sd = sigf(dv / RELAX);
        float tv = (float)((nzw[rr] >> (j & 63)) & 1ULL);
        vals[0] += sp * sd * tv;                  // A
        vals[1] += sp * tv;                       // B
        vals[2] += sp * sd;                       // A'
        vals[3] += sp;                            // B'
        vals[4] += fgv[rr] ? 0.0f : sp;           // C' = sp*(1-fat)
        vals[5] += tv;                            // T
        vals[6] = fminf(vals[6], dv);
        vals[7] = fmaxf(vals[7], dv);
    }
    for (int off = 32; off > 0; off >>= 1) {
        #pragma unroll
        for (int qq = 0; qq < 6; ++qq) vals[qq] += __shfl_down(vals[qq], off, 64);
        vals[6] = fminf(vals[6], __shfl_down(vals[6], off, 64));
        vals[7] = fmaxf(vals[7], __shfl_down(vals[7], off, 64));
    }
    if (lane == 0) {
        #pragma unroll
        for (int qq = 0; qq < 8; ++qq) red[qq][wv] = vals[qq];
    }
    __syncthreads();
    if (tid == 0) {
        float s[8];
        #pragma unroll
        for (int qq = 0; qq < 6; ++qq) {
            s[qq] = 0.0f;
            #pragma unroll
            for (int k = 0; k < 8; ++k) s[qq] += red[qq][k];
        }
        s[6] = red[6][0]; s[7] = red[7][0];
        #pragma unroll
        for (int k = 1; k < 8; ++k) {
            s[6] = fminf(s[6], red[6][k]);
            s[7] = fmaxf(s[7], red[7][k]);
        }
        part1[blk] = make_float4(s[0], s[1], s[2], s[3]);
        part2[blk] = make_float4(s[4], s[5], s[6], s[7]);
        __threadfence();                          // release partials
        stick = atomicAdd(&cnt[0], 1u);
    }
    __syncthreads();
    if (stick != MEGA_BLOCKS - 1) return;

    // ---- fused tail: last block folds 32 partials/image (proven pattern) ----
    __threadfence();                              // acquire partials
    #pragma unroll
    for (int pass = 0; pass < 2; ++pass) {
        int img = pass * 16 + (tid >> 5);         // 16 images per pass, 32 lanes each
        int k = tid & 31;
        float4 p1 = part1[img * 32 + k];
        float4 p2 = part2[img * 32 + k];
        float v2[8] = {p1.x, p1.y, p1.z, p1.w, p2.x, p2.y, p2.z, p2.w};
        for (int off = 16; off > 0; off >>= 1) {
            #pragma unroll
            for (int qq = 0; qq < 6; ++qq) v2[qq] += __shfl_down(v2[qq], off, 32);
            v2[6] = fminf(v2[6], __shfl_down(v2[6], off, 32));
            v2[7] = fmaxf(v2[7], __shfl_down(v2[7], off, 32));
        }
        if (k == 0) {
            float A = v2[0], Bs = v2[1], Ap = v2[2], Bp = v2[3];
            float Cp = v2[4], T = v2[5], dmn = v2[6], dmx = v2[7];
            float inter, card, any;
            if (dmx > 0.0f) {          // image has foreground
                float smin = sigf(dmn / RELAX);
                float smax = sigf(dmx / RELAX);
                float m = smax - smin;
                float denom = (m > 0.0f) ? m : 1.0f;
                inter = (A - smin * Bs) / denom;   // Σ sp·t·(1-fat) == 0 exactly
                card  = (Ap - smin * Bp) / denom + K_BG * Cp + T;
                any = 1.0f;
            } else {                   // dm = 1 - t ; t == 0 everywhere
                inter = 0.0f;
                card = Bp - Bs + T;
                any = 0.0f;
            }
            sI[img] = inter; sC[img] = card; sA[img] = any;
        }
    }
    __syncthreads();
    if (tid == 0) {
        double I = 0.0, C = 0.0;
        int any = 0;
        for (int bb = 0; bb < BB; ++bb) {
            I += (double)sI[bb]; C += (double)sC[bb];
            any |= (sA[bb] > 0.0f);
        }
        double dice = 2.0 * I / fmax(C, (double)EPS_D);
        out[0] = any ? (float)(1.0 - dice) : 0.0f;
    }
}

extern "C" void kernel_launch(void* const* d_in, const int* in_sizes, int n_in,
                              void* d_out, int out_size, void* d_ws, size_t ws_size,
                              hipStream_t stream) {
    const float* preds = (const float*)d_in[0];
    const float* tg    = (const float*)d_in[1];
    float* out = (float*)d_out;

    u64* dmaskT   = (u64*)d_ws;                      // 256 KB
    u64* nzmask   = dmaskT + BB * 1024;              // 256 KB
    float4* part1 = (float4*)(nzmask + BB * 1024);   // 16 KB, 16B-aligned
    float4* part2 = part1 + MEGA_BLOCKS;             // 16 KB
    unsigned* cnt = (unsigned*)(part2 + MEGA_BLOCKS);

    hipLaunchKernelGGL(k_maskdil, dim3(BB * 16), dim3(WW), 0, stream,
                       tg, dmaskT, nzmask, cnt);
    hipLaunchKernelGGL(k_mega, dim3(MEGA_BLOCKS), dim3(512), 0, stream,
                       preds, dmaskT, nzmask, part1, part2, cnt, out);
}

// Round 8
// 93.785 us; speedup vs baseline: 2.3458x; 1.0468x over previous
//
#include <hip/hip_runtime.h>
#include <math.h>

#define BB 32
#define HH 256
#define WW 256
#define HW (HH*WW)
#define K_BG 0.1f
#define RELAX 5.0f
#define EPS_D 1e-7
#define RPB 8                          // rows per k_mega BLOCK (amortization unit)
#define RPT 4                          // rows per THREAD (512-thread blocks)
#define MEGA_BLOCKS (BB * (HH / RPB))  // 1024 blocks x 512 thr = 2048 thr/CU (full)
#define GP 8                           // gS guard pad (columns each side)

typedef unsigned long long u64;

// fast sigmoid: 1/(1+2^(-x*log2e)); v_exp_f32+v_rcp_f32, |err|~1e-6 << 1.8e-2 thr
__device__ __forceinline__ float sigf(float x) {
    float e = __builtin_amdgcn_exp2f(-1.44269504f * x);
    return __builtin_amdgcn_rcpf(1.0f + e);
}

__device__ __forceinline__ u64 shflx64(u64 x, int s) {
    return (u64)__shfl_xor((unsigned long long)x, s, 64);
}

// ---------------- binary 5x5 dilation as bit-ops -> row masks ----------------
// R0/R5-proven structure: 512 blocks x 256 threads (16-row bands).
__global__ void k_maskdil(const float* __restrict__ tg, u64* __restrict__ dmaskT,
                          u64* __restrict__ nzmask, unsigned* __restrict__ cnt) {
    __shared__ u64 nz[20][4];
    __shared__ u64 hd[20][4];
    int blk = blockIdx.x;              // 32 images x 16 bands of 16 rows
    int b = blk >> 4, band = blk & 15;
    int r0 = band * 16;
    int t = threadIdx.x, w = t >> 6;
    const float* img = tg + b * HW;
    if (blk == 0 && t == 0) cnt[0] = 0;      // ticket reset (R5-proven)
    float v[20];
    #pragma unroll
    for (int rr = 0; rr < 20; ++rr) {
        int rg = r0 + rr - 2;
        v[rr] = (rg >= 0 && rg < HH) ? img[rg * WW + t] : 0.0f;
    }
    #pragma unroll
    for (int rr = 0; rr < 20; ++rr) {
        u64 bal = __ballot(v[rr] != 0.0f);
        if ((t & 63) == 0) nz[rr][w] = bal;
    }
    __syncthreads();
    if (t < 80) {                      // 20 rows x 4 words: horizontal +-2 dilate
        int rr = t >> 2, k = t & 3;
        u64 m = nz[rr][k];
        u64 ml = (k > 0) ? nz[rr][k - 1] : 0ULL;
        u64 mr = (k < 3) ? nz[rr][k + 1] : 0ULL;
        hd[rr][k] = m | (m << 1) | (m << 2) | (m >> 1) | (m >> 2)
                  | (ml >> 62) | (ml >> 63) | (mr << 62) | (mr << 63);
    }
    if (t < 64) {                      // raw masks for the 16 owned rows
        int rr = t >> 2, k = t & 3;
        nzmask[b * 1024 + (r0 + rr) * 4 + k] = nz[rr + 2][k];
    }
    __syncthreads();
    if (t < 64) {                      // 16 rows x 4 words: vertical +-2 dilate
        int rr = t >> 2, k = t & 3;
        u64 o = hd[rr][k] | hd[rr + 1][k] | hd[rr + 2][k] | hd[rr + 3][k] | hd[rr + 4][k];
        dmaskT[b * 1024 + k * 256 + (r0 + rr)] = o;   // word-major
    }
}

// ---------------- mega: 512 threads, full occupancy (R7-proven) ---------------
// R7 post-mortem: the ~44us "overhead" is the harness's 256MiB workspace
// re-poison fill (HBM-bound, untouchable). mega is the only controllable cost.
// R8 cuts: prefix 8->4 + chunk test from rc=5 (fat density ~22% -> best<25
// nearly always; halves guaranteed walk LDS reads, exactness preserved since
// the rc test only needs candidates r<rc); guard-padded gS (no bounds cndmask
// in prefix); fast sigmoid/sqrt (v_exp/v_rcp/v_sqrt; err ~1e-6 << 1.8e-2 thr);
// fold gated on T>0 (== reference has_fg; dmx>0 was wrong for no-fg images).
__global__ __launch_bounds__(512, 8) void k_mega(const float* __restrict__ preds,
                                                 const u64* __restrict__ dmaskT,
                                                 const u64* __restrict__ nzmask,
                                                 float4* __restrict__ part1,
                                                 float4* __restrict__ part2,
                                                 unsigned* __restrict__ cnt,
                                                 float* __restrict__ out) {
    __shared__ u64 colT[4 * 256];      // [rowgroup g][col] : bits = rows 64g..64g+63
    __shared__ float gS[RPB][WW + 2 * GP];
    __shared__ float red[8][8];
    __shared__ unsigned stick;
    __shared__ float sI[BB], sC[BB], sA[BB];
    int blk = blockIdx.x;              // b*32 + q ; rows 8q..8q+7
    int b = blk >> 5, q = blk & 31;
    int i0 = q * RPB;
    int tid = threadIdx.x;
    int lane = tid & 63, wv = tid >> 6;      // 8 waves
    int j = tid & 255;                 // this thread's column
    int r0t = (tid >> 8) * RPT;        // row-half: 0 or 4

    float p[RPT];                      // issue HBM loads first; consumed much later
    #pragma unroll
    for (int rr = 0; rr < RPT; ++rr)
        p[rr] = preds[(b * HH + i0 + r0t + rr) * WW + j];
    int wj = j >> 6;                   // word index of this column
    u64 nzw[RPT];
    #pragma unroll
    for (int rr = 0; rr < RPT; ++rr)
        nzw[rr] = nzmask[b * 1024 + (i0 + r0t + rr) * 4 + wj];

    if (tid < 128) {                   // gS guard columns: [0..7] and [264..271]
        int rr = tid >> 4, c = tid & 15;
        gS[rr][(c < 8) ? c : (c + 256)] = 1e4f;
    }

    // ---- register bit-transpose: 16 (g,w) tasks over 8 waves, 2 each ----
    const u64* base = dmaskT + b * 1024;
    const u64 L32 = 0x00000000FFFFFFFFULL, L16 = 0x0000FFFF0000FFFFULL,
              L8  = 0x00FF00FF00FF00FFULL, L4  = 0x0F0F0F0F0F0F0F0FULL,
              L2  = 0x3333333333333333ULL, L1  = 0x5555555555555555ULL;
    int tg_ = wv & 3, w0 = (wv >> 2) * 2;
    #pragma unroll
    for (int dw = 0; dw < 2; ++dw) {
        int w = w0 + dw;
        u64 x = base[w * 256 + tg_ * 64 + lane];  // row (64g+lane), word w
        u64 pp;
        pp = shflx64(x, 32); x = (lane & 32) ? ((x & ~L32) | ((pp & ~L32) >> 32)) : ((x & L32) | ((pp & L32) << 32));
        pp = shflx64(x, 16); x = (lane & 16) ? ((x & ~L16) | ((pp & ~L16) >> 16)) : ((x & L16) | ((pp & L16) << 16));
        pp = shflx64(x,  8); x = (lane &  8) ? ((x & ~L8 ) | ((pp & ~L8 ) >>  8)) : ((x & L8 ) | ((pp & L8 ) <<  8));
        pp = shflx64(x,  4); x = (lane &  4) ? ((x & ~L4 ) | ((pp & ~L4 ) >>  4)) : ((x & L4 ) | ((pp & L4 ) <<  4));
        pp = shflx64(x,  2); x = (lane &  2) ? ((x & ~L2 ) | ((pp & ~L2 ) >>  2)) : ((x & L2 ) | ((pp & L2 ) <<  2));
        pp = shflx64(x,  1); x = (lane &  1) ? ((x & ~L1 ) | ((pp & ~L1 ) >>  1)) : ((x & L1 ) | ((pp & L1 ) <<  1));
        colT[tg_ * 256 + w * 64 + lane] = x;      // column (64w+lane), rowgroup g
    }
    __syncthreads();

    u64 yw[4];                         // set bit = zero pixel, column j
    #pragma unroll
    for (int g = 0; g < 4; ++g) yw[g] = ~colT[g * 256 + j];

    // ---- vertical distance for this thread's 4 rows, with wave-skip ----
    int g0v[RPT], fgv[RPT], needw[RPT];
    #pragma unroll
    for (int rr = 0; rr < RPT; ++rr) {
        int i = i0 + r0t + rr;
        int iw = i >> 6, ib = i & 63;
        int fg = (int)((~yw[iw] >> ib) & 1ULL);   // 1 = fat pixel
        fgv[rr] = fg;
        u64 anyf = __ballot(fg != 0);             // wave-row fat occupancy
        needw[rr] = (anyf != 0ULL);
        int g0 = 0;
        if (anyf) {                               // ~76% of wave-rows
            u64 lowm  = (2ULL << ib) - 1ULL;      // bits 0..ib (ib=63 -> ~0)
            u64 highm = ~((1ULL << ib) - 1ULL);   // bits ib..63
            int pu = -1, pd = -1;
            #pragma unroll
            for (int w = 0; w < 4; ++w) {         // ascending: highest nonzero wins
                u64 m = (w < iw) ? ~0ULL : ((w == iw) ? lowm : 0ULL);
                u64 z = yw[w] & m;
                int cand = (w << 6) + 63 - __clzll(z);
                pu = z ? cand : pu;
            }
            #pragma unroll
            for (int w = 3; w >= 0; --w) {        // descending: lowest nonzero wins
                u64 m = (w > iw) ? ~0ULL : ((w == iw) ? highm : 0ULL);
                u64 z = yw[w] & m;
                int cand = (w << 6) + (__ffsll((unsigned long long)z) - 1);
                pd = z ? cand : pd;
            }
            int up = (pu >= 0) ? (i - pu) : 10000;
            int dn = (pd >= 0) ? (pd - i) : 10000;
            g0 = min(min(up, dn), 10000);
        }
        g0v[rr] = g0;
        gS[r0t + rr][GP + j] = (float)g0;
    }
    __syncthreads();

    // ---- min-plus walk: prefix r<=4 (guard-padded, no bounds) + rare tail ----
    float vals[8];
    #pragma unroll
    for (int qq = 0; qq < 6; ++qq) vals[qq] = 0.0f;
    vals[6] = 1e30f; vals[7] = 0.0f;
    #pragma unroll
    for (int rr = 0; rr < RPT; ++rr) {
        int rt = r0t + rr;
        const float* gr = &gS[rt][GP + j];
        float gv = (float)g0v[rr];
        float best = gv * gv;
        if (needw[rr]) {
            #pragma unroll
            for (int r = 1; r <= 4; ++r) {        // branchless prefix, no cndmask
                float rf = (float)(r * r);
                float vl = gr[-r], vr = gr[r];
                best = fminf(best, fminf(fmaf(vl, vl, rf), fmaf(vr, vr, rf)));
            }
            for (int rc = 5; rc < WW + 8; rc += 8) {  // exact tail, 1 test/chunk
                if ((float)(rc * rc) >= best) break;  // valid: best has all r<rc
                #pragma unroll
                for (int dr = 0; dr < 8; ++dr) {
                    int r = rc + dr;
                    float rf = (float)(r * r);
                    int jl = j - r, jr = j + r;
                    float vl = (jl >= 0) ? gr[-r] : 1e4f;
                    float vr = (jr < WW) ? gr[r] : 1e4f;
                    best = fminf(best, fminf(fmaf(vl, vl, rf), fmaf(vr, vr, rf)));
                }
            }
        }
        float dv = __builtin_amdgcn_sqrtf(best);
        float sp = sigf(p[rr]);
        float sd = sigf(dv * (1.0f / RELAX));
        float tv = (float)((nzw[rr] >> (j & 63)) & 1ULL);
        vals[0] += sp * sd * tv;                  // A
        vals[1] += sp * tv;                       // B
        vals[2] += sp * sd;                       // A'
        vals[3] += sp;                            // B'
        vals[4] += fgv[rr] ? 0.0f : sp;           // C' = sp*(1-fat)
        vals[5] += tv;                            // T
        vals[6] = fminf(vals[6], dv);
        vals[7] = fmaxf(vals[7], dv);
    }
    for (int off = 32; off > 0; off >>= 1) {
        #pragma unroll
        for (int qq = 0; qq < 6; ++qq) vals[qq] += __shfl_down(vals[qq], off, 64);
        vals[6] = fminf(vals[6], __shfl_down(vals[6], off, 64));
        vals[7] = fmaxf(vals[7], __shfl_down(vals[7], off, 64));
    }
    if (lane == 0) {
        #pragma unroll
        for (int qq = 0; qq < 8; ++qq) red[qq][wv] = vals[qq];
    }
    __syncthreads();
    if (tid == 0) {
        float s[8];
        #pragma unroll
        for (int qq = 0; qq < 6; ++qq) {
            s[qq] = 0.0f;
            #pragma unroll
            for (int k = 0; k < 8; ++k) s[qq] += red[qq][k];
        }
        s[6] = red[6][0]; s[7] = red[7][0];
        #pragma unroll
        for (int k = 1; k < 8; ++k) {
            s[6] = fminf(s[6], red[6][k]);
            s[7] = fmaxf(s[7], red[7][k]);
        }
        part1[blk] = make_float4(s[0], s[1], s[2], s[3]);
        part2[blk] = make_float4(s[4], s[5], s[6], s[7]);
        __threadfence();                          // release partials
        stick = atomicAdd(&cnt[0], 1u);
    }
    __syncthreads();
    if (stick != MEGA_BLOCKS - 1) return;

    // ---- fused tail: last block folds 32 partials/image (proven pattern) ----
    __threadfence();                              // acquire partials
    #pragma unroll
    for (int pass = 0; pass < 2; ++pass) {
        int img = pass * 16 + (tid >> 5);         // 16 images per pass, 32 lanes each
        int k = tid & 31;
        float4 p1 = part1[img * 32 + k];
        float4 p2 = part2[img * 32 + k];
        float v2[8] = {p1.x, p1.y, p1.z, p1.w, p2.x, p2.y, p2.z, p2.w};
        for (int off = 16; off > 0; off >>= 1) {
            #pragma unroll
            for (int qq = 0; qq < 6; ++qq) v2[qq] += __shfl_down(v2[qq], off, 32);
            v2[6] = fminf(v2[6], __shfl_down(v2[6], off, 32));
            v2[7] = fmaxf(v2[7], __shfl_down(v2[7], off, 32));
        }
        if (k == 0) {
            float A = v2[0], Bs = v2[1], Ap = v2[2], Bp = v2[3];
            float Cp = v2[4], T = v2[5], dmn = v2[6], dmx = v2[7];
            float inter, card, any;
            if (T > 0.0f) {            // has_fg == (sum targets > 0), as reference
                float smin = sigf(dmn * (1.0f / RELAX));
                float smax = sigf(dmx * (1.0f / RELAX));
                float m = smax - smin;
                float denom = (m > 0.0f) ? m : 1.0f;
                inter = (A - smin * Bs) / denom;   // Σ sp·t·(1-fat) == 0 exactly
                card  = (Ap - smin * Bp) / denom + K_BG * Cp + T;
                any = 1.0f;
            } else {                   // dm = 1 - t ; t == 0 everywhere
                inter = 0.0f;
                card = Bp - Bs + T;
                any = 0.0f;
            }
            sI[img] = inter; sC[img] = card; sA[img] = any;
        }
    }
    __syncthreads();
    if (tid == 0) {
        double I = 0.0, C = 0.0;
        int any = 0;
        for (int bb = 0; bb < BB; ++bb) {
            I += (double)sI[bb]; C += (double)sC[bb];
            any |= (sA[bb] > 0.0f);
        }
        double dice = 2.0 * I / fmax(C, (double)EPS_D);
        out[0] = any ? (float)(1.0 - dice) : 0.0f;
    }
}

extern "C" void kernel_launch(void* const* d_in, const int* in_sizes, int n_in,
                              void* d_out, int out_size, void* d_ws, size_t ws_size,
                              hipStream_t stream) {
    const float* preds = (const float*)d_in[0];
    const float* tg    = (const float*)d_in[1];
    float* out = (float*)d_out;

    u64* dmaskT   = (u64*)d_ws;                      // 256 KB
    u64* nzmask   = dmaskT + BB * 1024;              // 256 KB
    float4* part1 = (float4*)(nzmask + BB * 1024);   // 16 KB, 16B-aligned
    float4* part2 = part1 + MEGA_BLOCKS;             // 16 KB
    unsigned* cnt = (unsigned*)(part2 + MEGA_BLOCKS);

    hipLaunchKernelGGL(k_maskdil, dim3(BB * 16), dim3(WW), 0, stream,
                       tg, dmaskT, nzmask, cnt);
    hipLaunchKernelGGL(k_mega, dim3(MEGA_BLOCKS), dim3(512), 0, stream,
                       preds, dmaskT, nzmask, part1, part2, cnt, out);
}